// Round 1
// baseline (173.882 us; speedup 1.0000x reference)
//
#include <hip/hip_runtime.h>
#include <math.h>

#define B_ 64
#define T_ 256
#define K_ 128
#define S_ 8
#define SEG_ 32

typedef float f32x4 __attribute__((ext_vector_type(4)));
typedef short bf16x8 __attribute__((ext_vector_type(8)));

static __device__ __forceinline__ unsigned int bf16rne(float x) {
    unsigned int u = __builtin_bit_cast(unsigned int, x);
    return (u + 0x7FFFu + ((u >> 16) & 1u)) >> 16;
}
static __device__ __forceinline__ unsigned int pkbf16(float a, float b) {
    return bf16rne(a) | (bf16rne(b) << 16);
}
static __device__ __forceinline__ float bf2f(unsigned short h) {
    return __builtin_bit_cast(float, (unsigned int)h << 16);
}

// ---------------------------------------------------------------------------
// Phase 1: per-(batch, segment) transfer matrix M_s = prod_{t in seg} diag(ey_t)*Texp
// Grid B_*S_ = 512 blocks, 256 threads (4 waves), 2 blocks/CU (64KB LDS).
// Wave w owns output rows [32w, 32w+32): 2 mt x 8 nt x 4 kt = 64 MFMA/step.
// M kept bf16 in LDS, layout Ml[c][i] = M[i][c] (c = column of M, i contiguous),
// XOR-swizzled: phys_byte(c, i) = c*256 + ((2*i) ^ ((c&7)<<4)).  Scalar renorm
// every 4 steps via deferred partial sums (written tt%4==3, consumed tt%4==0).
// ---------------------------------------------------------------------------
__global__ __launch_bounds__(256, 2) void crf_seg_kernel(
    const float* __restrict__ y,
    const float* __restrict__ mask,
    const float* __restrict__ trans,
    unsigned short* __restrict__ Mout,   // [B][S][128][128] bf16, row c, entry i
    float* __restrict__ Cout)            // [B][S] accumulated log-scales
{
    const int bs   = blockIdx.x;
    const int b    = bs >> 3;
    const int s    = bs & 7;
    const int tid  = threadIdx.x;
    const int w    = tid >> 6;
    const int lane = tid & 63;
    const int q    = lane >> 4;
    const int ci   = lane & 15;

    __shared__ __align__(16) unsigned short Ml[2][K_ * K_];  // 64 KB double buffer
    __shared__ __align__(16) float wsumS[4];
    __shared__ int lenS[4];

    // ---- sequence length (mask is a contiguous 1.0 prefix) ----
    {
        float mval = mask[b * T_ + tid];
        unsigned long long bal = __ballot(mval != 0.0f);
        if (lane == 0) lenS[w] = __popcll(bal);
    }

    // ---- identity into Ml[0] (swizzled). lane covers (c, 16B chunk j) ----
    #pragma unroll
    for (int pass = 0; pass < 8; ++pass) {
        const int c = pass * 16 + (tid >> 4);
        const int j = tid & 15;
        unsigned int wds[4] = {0u, 0u, 0u, 0u};
        const int d = c - 8 * j;                 // entry i = 8j+d
        if (d >= 0 && d < 8) wds[d >> 1] = (d & 1) ? 0x3F800000u : 0x00003F80u;
        uint4 u4 = make_uint4(wds[0], wds[1], wds[2], wds[3]);
        *(uint4*)((char*)Ml + c * 256 + ((16 * j) ^ ((c & 7) << 4))) = u4;
    }

    // ---- A-frags: Texp rows 32w+16mt+ci, A[m=ci][k=8q+j] (proven layout) ----
    bf16x8 A[2][4];
    #pragma unroll
    for (int mt = 0; mt < 2; ++mt) {
        const float* tp = trans + (32 * w + 16 * mt + ci) * K_;
        #pragma unroll
        for (int kt = 0; kt < 4; ++kt) {
            f32x4 p = *(const f32x4*)(tp + 32 * kt + 8 * q);
            f32x4 r = *(const f32x4*)(tp + 32 * kt + 8 * q + 4);
            uint4 u = make_uint4(pkbf16(__expf(p.x), __expf(p.y)),
                                 pkbf16(__expf(p.z), __expf(p.w)),
                                 pkbf16(__expf(r.x), __expf(r.y)),
                                 pkbf16(__expf(r.z), __expf(r.w)));
            A[mt][kt] = __builtin_bit_cast(bf16x8, u);
        }
    }

    __syncthreads();
    const int L = lenS[0] + lenS[1] + lenS[2] + lenS[3];
    int ns = L - SEG_ * s;
    ns = ns < 0 ? 0 : (ns > SEG_ ? SEG_ : ns);

    float c_acc = 0.0f;
    int cur = 0;
    const float* yb = y + ((size_t)b * T_ + SEG_ * s) * K_ + 32 * w + 4 * q;
    f32x4 p0, p1, n0, n1;
    if (ns > 0) { p0 = *(const f32x4*)yb; p1 = *(const f32x4*)(yb + 16); }

    const int roff = ci << 8;
    const int swz  = (ci & 7) << 4;

    for (int tt = 0; tt < ns; ++tt) {
        if (tt + 1 < ns) {                       // prefetch next step's y (global)
            const float* yn = yb + (size_t)(tt + 1) * K_;
            n0 = *(const f32x4*)yn; n1 = *(const f32x4*)(yn + 16);
        }
        f32x4 ey0, ey1;
        ey0.x = __expf(p0.x); ey0.y = __expf(p0.y);
        ey0.z = __expf(p0.z); ey0.w = __expf(p0.w);
        ey1.x = __expf(p1.x); ey1.y = __expf(p1.y);
        ey1.z = __expf(p1.z); ey1.w = __expf(p1.w);

        if ((tt & 3) == 0 && tt) {               // consume partials from tt-1
            f32x4 ws4 = *(const f32x4*)wsumS;
            float S = (ws4.x + ws4.y) + (ws4.z + ws4.w);
            float rinv = __builtin_amdgcn_rcpf(S);
            c_acc += __logf(S);
            ey0 *= rinv; ey1 *= rinv;            // fold renorm into row scale
        }

        // ---- W = Texp * M : 64 MFMA, B from swizzled LDS ----
        const char* mb = (const char*)Ml + (cur << 15);
        f32x4 C0[8], C1[8];
        #pragma unroll
        for (int nt = 0; nt < 8; ++nt) {
            C0[nt] = (f32x4){0.f, 0.f, 0.f, 0.f};
            C1[nt] = (f32x4){0.f, 0.f, 0.f, 0.f};
        }
        #pragma unroll
        for (int kt = 0; kt < 4; ++kt) {
            const int koff = ((64 * kt + 16 * q) ^ swz) + roff;
            #pragma unroll
            for (int nt = 0; nt < 8; ++nt) {
                bf16x8 Bf = *(const bf16x8*)(mb + (nt << 12) + koff);
                C0[nt] = __builtin_amdgcn_mfma_f32_16x16x32_bf16(A[0][kt], Bf, C0[nt], 0, 0, 0);
                C1[nt] = __builtin_amdgcn_mfma_f32_16x16x32_bf16(A[1][kt], Bf, C1[nt], 0, 0, 0);
            }
        }

        // ---- scale rows by ey, pack bf16, write M' to other buffer ----
        char* mw = (char*)Ml + ((cur ^ 1) << 15);
        const int w0off = ((64 * w + 8 * q) ^ swz) + roff;        // mt=0
        const int w1off = ((64 * w + 32 + 8 * q) ^ swz) + roff;   // mt=1
        #pragma unroll
        for (int nt = 0; nt < 8; ++nt) {
            C0[nt] *= ey0;
            C1[nt] *= ey1;
            uint2 d0 = make_uint2(pkbf16(C0[nt].x, C0[nt].y), pkbf16(C0[nt].z, C0[nt].w));
            uint2 d1 = make_uint2(pkbf16(C1[nt].x, C1[nt].y), pkbf16(C1[nt].z, C1[nt].w));
            *(uint2*)(mw + (nt << 12) + w0off) = d0;
            *(uint2*)(mw + (nt << 12) + w1off) = d1;
        }

        if ((tt & 3) == 3) {                     // publish partial sums
            float t2 = 0.f;
            #pragma unroll
            for (int nt = 0; nt < 8; ++nt) {
                t2 += (C0[nt].x + C0[nt].y) + (C0[nt].z + C0[nt].w);
                t2 += (C1[nt].x + C1[nt].y) + (C1[nt].z + C1[nt].w);
            }
            t2 += __shfl_xor(t2, 1);  t2 += __shfl_xor(t2, 2);
            t2 += __shfl_xor(t2, 4);  t2 += __shfl_xor(t2, 8);
            t2 += __shfl_xor(t2, 16); t2 += __shfl_xor(t2, 32);
            if (lane == 0) wsumS[w] = t2;
        }

        __syncthreads();
        cur ^= 1;
        p0 = n0; p1 = n1;
    }

    // ---- epilogue: de-swizzle Ml[cur] -> global (coalesced 16B chunks) ----
    unsigned short* gout = Mout + ((size_t)bs << 14);
    #pragma unroll
    for (int pass = 0; pass < 8; ++pass) {
        const int c = pass * 16 + (tid >> 4);
        const int j = tid & 15;
        uint4 v = *(const uint4*)((const char*)Ml + (cur << 15) + c * 256 +
                                  ((16 * j) ^ ((c & 7) << 4)));
        *(uint4*)((char*)gout + c * 256 + 16 * j) = v;
    }
    if (tid == 0) Cout[bs] = c_acc;
}

// ---------------------------------------------------------------------------
// Phase 2: combine. One block per batch: u <- M_s * u for s = 0..7 with scalar
// renorm (u kept normalized to sum 1, so out[b] = sum of logs). Matrices staged
// via double-buffered LDS with register prefetch.
// ---------------------------------------------------------------------------
__global__ __launch_bounds__(256) void crf_comb_kernel(
    const unsigned short* __restrict__ Mseg,
    const float* __restrict__ Cseg,
    float* __restrict__ out)
{
    const int b    = blockIdx.x;
    const int tid  = threadIdx.x;
    const int lane = tid & 63;
    const int wv   = tid >> 6;

    __shared__ __align__(16) unsigned short Ms[2][K_ * K_];  // 64 KB
    __shared__ float uS[K_];
    __shared__ float tmp[256];
    __shared__ float red[2];

    if (tid < K_) uS[tid] = (tid == 2) ? 1.0f : 0.0f;

    float c_tot = 0.0f;
    uint4 R[8];
    {
        const uint4* src = (const uint4*)(Mseg + ((size_t)(b * S_) << 14));
        #pragma unroll
        for (int r = 0; r < 8; ++r) R[r] = src[tid + 256 * r];
    }

    for (int s = 0; s < S_; ++s) {
        uint4* dst = (uint4*)Ms[s & 1];
        #pragma unroll
        for (int r = 0; r < 8; ++r) dst[tid + 256 * r] = R[r];
        __syncthreads();                              // staged matrix + uS visible
        if (s + 1 < S_) {
            const uint4* nsrc = (const uint4*)(Mseg + ((size_t)(b * S_ + s + 1) << 14));
            #pragma unroll
            for (int r = 0; r < 8; ++r) R[r] = nsrc[tid + 256 * r];
        }

        // u'[i] = sum_c Ms[c][i] * u[c]; thread (h, i) covers half the c-range
        const int h = tid >> 7, i = tid & 127;
        const unsigned short* mrow = Ms[s & 1];
        float accA = 0.f, accB = 0.f;
        #pragma unroll 8
        for (int c = 64 * h; c < 64 * h + 64; c += 2) {
            accA += bf2f(mrow[c * K_ + i])       * uS[c];
            accB += bf2f(mrow[(c + 1) * K_ + i]) * uS[c + 1];
        }
        tmp[tid] = accA + accB;
        __syncthreads();

        float un = 0.f;
        if (tid < K_) un = tmp[tid] + tmp[tid + 128];
        float ps = un;
        ps += __shfl_xor(ps, 1);  ps += __shfl_xor(ps, 2);
        ps += __shfl_xor(ps, 4);  ps += __shfl_xor(ps, 8);
        ps += __shfl_xor(ps, 16); ps += __shfl_xor(ps, 32);
        if (lane == 0 && wv < 2) red[wv] = ps;
        __syncthreads();
        const float total = red[0] + red[1];
        const float rt = 1.0f / total;
        if (tid < K_) uS[tid] = un * rt;              // visible at next stage barrier
        c_tot += __logf(total) + Cseg[b * S_ + s];
    }

    if (tid == 0) out[b] = c_tot;                     // sum(u)==1 => log term is 0
}

extern "C" void kernel_launch(void* const* d_in, const int* in_sizes, int n_in,
                              void* d_out, int out_size, void* d_ws, size_t ws_size,
                              hipStream_t stream) {
    const float* y     = (const float*)d_in[0];   // (B, T, K) fp32
    const float* mask  = (const float*)d_in[1];   // (B, T)    fp32 0/1
    const float* trans = (const float*)d_in[2];   // (K, K)    fp32
    float* out = (float*)d_out;                   // (B,)      fp32

    unsigned short* Mws = (unsigned short*)d_ws;                       // 16.78 MB
    float* Cws = (float*)((char*)d_ws + (size_t)B_ * S_ * K_ * K_ * 2);

    crf_seg_kernel<<<B_ * S_, 256, 0, stream>>>(y, mask, trans, Mws, Cws);
    crf_comb_kernel<<<B_, 256, 0, stream>>>(Mws, Cws, out);
}